// Round 1
// baseline (423.255 us; speedup 1.0000x reference)
//
#include <hip/hip_runtime.h>
#include <hip/hip_bf16.h>

#define BATCH 8
#define NN 2048
#define FI 256
#define FO 256
#define ALPHA 0.2f
#define NEG_BIG -9000000000000000.0f

typedef short bf16x8 __attribute__((ext_vector_type(8)));
typedef float floatx4 __attribute__((ext_vector_type(4)));

// ---------------- Kernel A: h = x@W (fp32), fused s1/s2, write hT as bf16 ----
// block = 256 threads (thread t = output column o), 16 rows per block.
__global__ __launch_bounds__(256) void gemm_h_kernel(
    const float* __restrict__ x, const float* __restrict__ W, const float* __restrict__ a,
    unsigned short* __restrict__ hbT, float* __restrict__ s1, float* __restrict__ s2) {
  const int t = threadIdx.x;
  const int blk = blockIdx.x;
  const int b = blk >> 7;             // 128 blocks per batch (2048/16)
  const int n0 = (blk & 127) << 4;    // 16 rows
  __shared__ float4 xs[1024];         // 16 rows x 256 floats = 16 KB
  const float4* xg = (const float4*)(x + (size_t)(b * NN + n0) * FI);
  #pragma unroll
  for (int idx = t; idx < 1024; idx += 256) xs[idx] = xg[idx];
  __syncthreads();
  float acc[16];
  #pragma unroll
  for (int r = 0; r < 16; ++r) acc[r] = 0.f;
  for (int f4 = 0; f4 < 64; ++f4) {
    const float w0 = W[(4*f4+0)*FO + t];
    const float w1 = W[(4*f4+1)*FO + t];
    const float w2 = W[(4*f4+2)*FO + t];
    const float w3 = W[(4*f4+3)*FO + t];
    #pragma unroll
    for (int r = 0; r < 16; ++r) {
      const float4 xv = xs[r*64 + f4];   // same addr across lanes -> LDS broadcast
      acc[r] = fmaf(xv.x, w0, acc[r]);
      acc[r] = fmaf(xv.y, w1, acc[r]);
      acc[r] = fmaf(xv.z, w2, acc[r]);
      acc[r] = fmaf(xv.w, w3, acc[r]);
    }
  }
  // fused s1 = h@a1, s2 = h@a2 (block-wide reduction over the 256 columns)
  const float a1t = a[t], a2t = a[FO + t];
  __shared__ float red1[16][4];
  __shared__ float red2[16][4];
  const int lane = t & 63, wv = t >> 6;
  #pragma unroll
  for (int r = 0; r < 16; ++r) {
    float v1 = acc[r]*a1t, v2 = acc[r]*a2t;
    #pragma unroll
    for (int s = 32; s > 0; s >>= 1) { v1 += __shfl_xor(v1, s); v2 += __shfl_xor(v2, s); }
    if (lane == 0) { red1[r][wv] = v1; red2[r][wv] = v2; }
  }
  __syncthreads();
  if (t < 16) {
    s1[b*NN + n0 + t] = red1[t][0]+red1[t][1]+red1[t][2]+red1[t][3];
    s2[b*NN + n0 + t] = red2[t][0]+red2[t][1]+red2[t][2]+red2[t][3];
  }
  // write hT (bf16): hbT[b][o=t][n0..n0+15] -- 32B contiguous per thread
  __align__(16) unsigned short hb[16];
  #pragma unroll
  for (int r = 0; r < 16; ++r)
    hb[r] = __builtin_bit_cast(unsigned short, __float2bfloat16(acc[r]));
  uint4* dst = (uint4*)(hbT + (size_t)(b*FO + t)*NN + n0);
  dst[0] = *(const uint4*)&hb[0];
  dst[1] = *(const uint4*)&hb[8];
}

// ---------------- Kernel B: column softmax partial stats + adjacency bitmask --
// grid (jt=8, ic=8, b=8); block 256 = 4 waves, wave owns 64 columns j.
__global__ __launch_bounds__(256) void stats_kernel(
    const int* __restrict__ adj, const float* __restrict__ s1, const float* __restrict__ s2,
    unsigned long long* __restrict__ mask, float* __restrict__ pm, float* __restrict__ pl) {
  const int t = threadIdx.x;
  const int wv = t >> 6, lane = t & 63;
  const int jt = blockIdx.x, ic = blockIdx.y, b = blockIdx.z;
  const int j = jt*256 + wv*64 + lane;
  const float s2j = s2[b*NN + j];
  float m = NEG_BIG, l = 0.f;
  const int i0 = ic*256;
  for (int i = i0; i < i0 + 256; ++i) {
    const int av = adj[(size_t)(b*NN + i)*NN + j];
    float e = s1[b*NN + i] + s2j;          // s1 load is wave-uniform (scalar)
    e = fmaxf(e, ALPHA*e);                 // leaky_relu
    const float v = (av > 0) ? e : NEG_BIG;
    const float nm = fmaxf(m, v);
    l = l*__expf(m - nm) + __expf(v - nm); // branchless online softmax
    m = nm;
    const unsigned long long bits = __ballot(av > 0);
    if (lane == 0) mask[(size_t)(b*NN + i)*32 + (jt*4 + wv)] = bits;
  }
  pm[(ic*BATCH + b)*NN + j] = m;
  pl[(ic*BATCH + b)*NN + j] = l;
}

// ---------------- Kernel B2: combine partials -> mpl = m + log(l) ------------
__global__ __launch_bounds__(256) void combine_kernel(
    const float* __restrict__ pm, const float* __restrict__ pl, float* __restrict__ mpl) {
  const int id = blockIdx.x*256 + threadIdx.x;  // 0 .. BATCH*NN
  float m = NEG_BIG;
  #pragma unroll
  for (int c = 0; c < 8; ++c) m = fmaxf(m, pm[c*(BATCH*NN) + id]);
  float l = 0.f;
  #pragma unroll
  for (int c = 0; c < 8; ++c) l += pl[c*(BATCH*NN) + id] * __expf(pm[c*(BATCH*NN) + id] - m);
  mpl[id] = m + __logf(l);   // l >= 1 always
}

// ---------------- Kernel C: out = elu(P @ h), P computed on the fly ----------
// grid (ot=2, it=32, b=8); block 256 = 4 waves; tile 64(i) x 128(o), BK=32.
__global__ __launch_bounds__(256) void agg_kernel(
    const unsigned long long* __restrict__ mask, const float* __restrict__ s1,
    const float* __restrict__ s2, const float* __restrict__ mpl,
    const unsigned short* __restrict__ hbT, float* __restrict__ out) {
  const int t = threadIdx.x;
  const int ot = blockIdx.x;   // o-tile 0..1
  const int it = blockIdx.y;   // i-tile 0..31
  const int b  = blockIdx.z;   // 0..7
  __shared__ __align__(16) unsigned short Pt[64*40];   // P tile, stride 40 (pad)
  __shared__ __align__(16) unsigned short Vt[128*40];  // hT tile [o][k]
  __shared__ float s2s[NN];
  __shared__ float mpls[NN];
  for (int idx = t; idx < NN; idx += 256) {
    s2s[idx]  = s2[b*NN + idx];
    mpls[idx] = mpl[b*NN + idx];
  }
  const int prow = t >> 2;            // 0..63: P row / V row
  const int kq = (t & 3) * 8;         // k chunk within BK=32
  const int i = it*64 + prow;
  const float s1i = s1[b*NN + i];
  const unsigned long long* mrow = mask + (size_t)(b*NN + i)*32;
  const unsigned short* vsrc0 = hbT + (size_t)(b*FO + ot*128 + prow)*NN;
  const unsigned short* vsrc1 = hbT + (size_t)(b*FO + ot*128 + prow + 64)*NN;
  const int lane = t & 63, wv = t >> 6;
  const int wr = (wv & 1)*32;         // wave quadrant: 32 rows x 64 cols
  const int wc = (wv >> 1)*64;
  const int ln = lane & 15, q8 = (lane >> 4)*8;
  floatx4 acc[2][4];
  #pragma unroll
  for (int mb = 0; mb < 2; ++mb)
    #pragma unroll
    for (int nb = 0; nb < 4; ++nb)
      acc[mb][nb] = (floatx4){0.f, 0.f, 0.f, 0.f};
  __syncthreads();
  for (int kt = 0; kt < NN/32; ++kt) {
    const int j0 = kt*32;
    const unsigned int bits =
        (unsigned int)(mrow[j0 >> 6] >> (j0 & 63)) >> kq;
    __align__(16) unsigned short pv[8];
    #pragma unroll
    for (int kk = 0; kk < 8; ++kk) {
      const int k = j0 + kq + kk;
      float e = s1i + s2s[k];
      e = fmaxf(e, ALPHA*e);
      const float vvv = ((bits >> kk) & 1u) ? e : NEG_BIG;
      pv[kk] = __builtin_bit_cast(unsigned short,
                 __float2bfloat16(__expf(vvv - mpls[k])));
    }
    *(uint4*)&Pt[prow*40 + kq] = *(const uint4*)pv;
    *(uint4*)&Vt[prow*40 + kq]      = *(const uint4*)(vsrc0 + j0 + kq);
    *(uint4*)&Vt[(prow+64)*40 + kq] = *(const uint4*)(vsrc1 + j0 + kq);
    __syncthreads();
    bf16x8 af[2], bfr[4];
    #pragma unroll
    for (int mb = 0; mb < 2; ++mb)
      af[mb] = *(const bf16x8*)&Pt[(wr + mb*16 + ln)*40 + q8];
    #pragma unroll
    for (int nb = 0; nb < 4; ++nb)
      bfr[nb] = *(const bf16x8*)&Vt[(wc + nb*16 + ln)*40 + q8];
    #pragma unroll
    for (int mb = 0; mb < 2; ++mb)
      #pragma unroll
      for (int nb = 0; nb < 4; ++nb)
        acc[mb][nb] = __builtin_amdgcn_mfma_f32_16x16x32_bf16(
            af[mb], bfr[nb], acc[mb][nb], 0, 0, 0);
    __syncthreads();
  }
  // epilogue: ELU + store. D layout: col = lane&15, row = (lane>>4)*4 + reg
  const int orow_base = it*64 + wr;
  const int ocol_base = ot*128 + wc;
  #pragma unroll
  for (int mb = 0; mb < 2; ++mb) {
    #pragma unroll
    for (int nb = 0; nb < 4; ++nb) {
      #pragma unroll
      for (int r = 0; r < 4; ++r) {
        float vvv = acc[mb][nb][r];
        vvv = vvv > 0.f ? vvv : (__expf(vvv) - 1.f);
        const int m_loc = orow_base + mb*16 + (lane >> 4)*4 + r;
        const int n_loc = ocol_base + nb*16 + ln;
        out[(size_t)(b*NN + m_loc)*FO + n_loc] = vvv;
      }
    }
  }
}

extern "C" void kernel_launch(void* const* d_in, const int* in_sizes, int n_in,
                              void* d_out, int out_size, void* d_ws, size_t ws_size,
                              hipStream_t stream) {
  const float* x  = (const float*)d_in[0];
  const int* adj  = (const int*)d_in[1];
  const float* W  = (const float*)d_in[2];
  const float* a  = (const float*)d_in[3];
  float* out = (float*)d_out;

  char* ws = (char*)d_ws;
  size_t off = 0;
  auto alloc = [&](size_t bytes) -> void* {
    void* p = ws + off; off += (bytes + 255) & ~(size_t)255; return p;
  };
  unsigned short* hbT      = (unsigned short*)alloc((size_t)BATCH*FO*NN*2);      // 8 MB
  float* s1                = (float*)alloc((size_t)BATCH*NN*4);
  float* s2                = (float*)alloc((size_t)BATCH*NN*4);
  float* pm                = (float*)alloc((size_t)8*BATCH*NN*4);
  float* pl                = (float*)alloc((size_t)8*BATCH*NN*4);
  float* mpl               = (float*)alloc((size_t)BATCH*NN*4);
  unsigned long long* mask = (unsigned long long*)alloc((size_t)BATCH*NN*(NN/64)*8); // 4 MB

  gemm_h_kernel<<<dim3(BATCH*NN/16), dim3(256), 0, stream>>>(x, W, a, hbT, s1, s2);
  stats_kernel<<<dim3(8, 8, 8), dim3(256), 0, stream>>>(adj, s1, s2, mask, pm, pl);
  combine_kernel<<<dim3(BATCH*NN/256), dim3(256), 0, stream>>>(pm, pl, mpl);
  agg_kernel<<<dim3(2, NN/64, BATCH), dim3(256), 0, stream>>>(mask, s1, s2, mpl, hbT, out);
}

// Round 2
// 343.726 us; speedup vs baseline: 1.2314x; 1.2314x over previous
//
#include <hip/hip_runtime.h>
#include <hip/hip_bf16.h>

#define BATCH 8
#define NN 2048
#define FI 256
#define FO 256
#define ALPHA 0.2f
#define NEG_BIG -9000000000000000.0f

typedef short bf16x8 __attribute__((ext_vector_type(8)));
typedef float floatx4 __attribute__((ext_vector_type(4)));

// ---------------- Kernel A: h = x@W (fp32), fused s1/s2, write hT as bf16 ----
__global__ __launch_bounds__(256) void gemm_h_kernel(
    const float* __restrict__ x, const float* __restrict__ W, const float* __restrict__ a,
    unsigned short* __restrict__ hbT, float* __restrict__ s1, float* __restrict__ s2) {
  const int t = threadIdx.x;
  const int blk = blockIdx.x;
  const int b = blk >> 7;             // 128 blocks per batch (2048/16)
  const int n0 = (blk & 127) << 4;    // 16 rows
  __shared__ float4 xs[1024];         // 16 rows x 256 floats = 16 KB
  const float4* xg = (const float4*)(x + (size_t)(b * NN + n0) * FI);
  #pragma unroll
  for (int idx = t; idx < 1024; idx += 256) xs[idx] = xg[idx];
  __syncthreads();
  float acc[16];
  #pragma unroll
  for (int r = 0; r < 16; ++r) acc[r] = 0.f;
  for (int f4 = 0; f4 < 64; ++f4) {
    const float w0 = W[(4*f4+0)*FO + t];
    const float w1 = W[(4*f4+1)*FO + t];
    const float w2 = W[(4*f4+2)*FO + t];
    const float w3 = W[(4*f4+3)*FO + t];
    #pragma unroll
    for (int r = 0; r < 16; ++r) {
      const float4 xv = xs[r*64 + f4];   // same addr across lanes -> LDS broadcast
      acc[r] = fmaf(xv.x, w0, acc[r]);
      acc[r] = fmaf(xv.y, w1, acc[r]);
      acc[r] = fmaf(xv.z, w2, acc[r]);
      acc[r] = fmaf(xv.w, w3, acc[r]);
    }
  }
  const float a1t = a[t], a2t = a[FO + t];
  __shared__ float red1[16][4];
  __shared__ float red2[16][4];
  const int lane = t & 63, wv = t >> 6;
  #pragma unroll
  for (int r = 0; r < 16; ++r) {
    float v1 = acc[r]*a1t, v2 = acc[r]*a2t;
    #pragma unroll
    for (int s = 32; s > 0; s >>= 1) { v1 += __shfl_xor(v1, s); v2 += __shfl_xor(v2, s); }
    if (lane == 0) { red1[r][wv] = v1; red2[r][wv] = v2; }
  }
  __syncthreads();
  if (t < 16) {
    s1[b*NN + n0 + t] = red1[t][0]+red1[t][1]+red1[t][2]+red1[t][3];
    s2[b*NN + n0 + t] = red2[t][0]+red2[t][1]+red2[t][2]+red2[t][3];
  }
  __align__(16) unsigned short hb[16];
  #pragma unroll
  for (int r = 0; r < 16; ++r)
    hb[r] = __builtin_bit_cast(unsigned short, __float2bfloat16(acc[r]));
  uint4* dst = (uint4*)(hbT + (size_t)(b*FO + t)*NN + n0);
  dst[0] = *(const uint4*)&hb[0];
  dst[1] = *(const uint4*)&hb[8];
}

// ---------------- Kernel M: pack adj>0 into bitmask (pure bandwidth) ---------
// word w covers adj flat elements [w*64, w*64+64); bit k = element w*64+k.
// 16 independent int4 loads per thread -> deep MLP, HBM-bound.
__global__ __launch_bounds__(256) void mask_kernel(
    const int* __restrict__ adj, unsigned long long* __restrict__ mask) {
  const size_t word = (size_t)blockIdx.x * 256 + threadIdx.x;  // 0..524287
  const int4* p = (const int4*)adj + word * 16;
  unsigned long long bits = 0;
  #pragma unroll
  for (int k = 0; k < 16; ++k) {
    const int4 v = p[k];
    const unsigned long long nib =
        (unsigned long long)(v.x != 0)
      | ((unsigned long long)(v.y != 0) << 1)
      | ((unsigned long long)(v.z != 0) << 2)
      | ((unsigned long long)(v.w != 0) << 3);
    bits |= nib << (4*k);
  }
  mask[word] = bits;
}

// ---------------- Kernel B: column softmax partials from bitmask -------------
// grid (jt=8, ic=8, b=8); block 256 = 4 waves; wave owns 64 consecutive j.
// leaky_relu is monotone => column max m = leaky(max masked s1[i] + s2[j]).
__global__ __launch_bounds__(256) void stats2_kernel(
    const unsigned long long* __restrict__ mask, const float* __restrict__ s1,
    const float* __restrict__ s2, float* __restrict__ pm, float* __restrict__ pl) {
  const int t = threadIdx.x;
  const int jt = blockIdx.x, ic = blockIdx.y, b = blockIdx.z;
  const int lane = t & 63, wv = t >> 6;
  const int i0 = ic * 256;
  __shared__ float s1s[256];
  __shared__ unsigned long long sm[256 * 4];  // [i][wv]
  s1s[t] = s1[b*NN + i0 + t];
  #pragma unroll
  for (int idx = t; idx < 1024; idx += 256) {
    const int i = idx >> 2, w = idx & 3;
    sm[idx] = mask[(size_t)(b*NN + i0 + i)*32 + jt*4 + w];
  }
  __syncthreads();
  const int j = jt*256 + wv*64 + lane;
  const float s2j = s2[b*NN + j];
  float M0 = NEG_BIG, M1 = NEG_BIG, M2 = NEG_BIG, M3 = NEG_BIG;
  for (int i = 0; i < 256; i += 4) {
    const bool o0 = (sm[(i+0)*4 + wv] >> lane) & 1ull;
    const bool o1 = (sm[(i+1)*4 + wv] >> lane) & 1ull;
    const bool o2 = (sm[(i+2)*4 + wv] >> lane) & 1ull;
    const bool o3 = (sm[(i+3)*4 + wv] >> lane) & 1ull;
    M0 = fmaxf(M0, o0 ? s1s[i+0] : NEG_BIG);
    M1 = fmaxf(M1, o1 ? s1s[i+1] : NEG_BIG);
    M2 = fmaxf(M2, o2 ? s1s[i+2] : NEG_BIG);
    M3 = fmaxf(M3, o3 ? s1s[i+3] : NEG_BIG);
  }
  const float M = fmaxf(fmaxf(M0, M1), fmaxf(M2, M3));
  float m;
  if (M == NEG_BIG) m = NEG_BIG;   // all-masked column -> uniform softmax path
  else { const float e = M + s2j; m = fmaxf(e, ALPHA*e); }
  float l0 = 0.f, l1 = 0.f, l2 = 0.f, l3 = 0.f;
  for (int i = 0; i < 256; i += 4) {
    #pragma unroll
    for (int u = 0; u < 4; ++u) {
      const bool on = (sm[(i+u)*4 + wv] >> lane) & 1ull;
      float e = s1s[i+u] + s2j;
      e = fmaxf(e, ALPHA*e);
      const float v = (on ? e : NEG_BIG) - m;   // off: -inf -> exp 0 (or 0 if m=NEG_BIG)
      const float ex = __expf(v);
      if (u == 0) l0 += ex; else if (u == 1) l1 += ex; else if (u == 2) l2 += ex; else l3 += ex;
    }
  }
  pm[(ic*BATCH + b)*NN + j] = m;
  pl[(ic*BATCH + b)*NN + j] = (l0 + l1) + (l2 + l3);
}

// ---------------- Kernel B2: combine partials -> mpl = m + log(l) ------------
__global__ __launch_bounds__(256) void combine_kernel(
    const float* __restrict__ pm, const float* __restrict__ pl, float* __restrict__ mpl) {
  const int id = blockIdx.x*256 + threadIdx.x;
  float m = NEG_BIG;
  #pragma unroll
  for (int c = 0; c < 8; ++c) m = fmaxf(m, pm[c*(BATCH*NN) + id]);
  float l = 0.f;
  #pragma unroll
  for (int c = 0; c < 8; ++c) l += pl[c*(BATCH*NN) + id] * __expf(pm[c*(BATCH*NN) + id] - m);
  mpl[id] = m + __logf(l);
}

// ---------------- Kernel C: out = elu(P @ h), P computed on the fly ----------
__global__ __launch_bounds__(256) void agg_kernel(
    const unsigned long long* __restrict__ mask, const float* __restrict__ s1,
    const float* __restrict__ s2, const float* __restrict__ mpl,
    const unsigned short* __restrict__ hbT, float* __restrict__ out) {
  const int t = threadIdx.x;
  const int ot = blockIdx.x;   // o-tile 0..1
  const int it = blockIdx.y;   // i-tile 0..31
  const int b  = blockIdx.z;   // 0..7
  __shared__ __align__(16) unsigned short Pt[64*40];
  __shared__ __align__(16) unsigned short Vt[128*40];
  __shared__ float s2s[NN];
  __shared__ float mpls[NN];
  for (int idx = t; idx < NN; idx += 256) {
    s2s[idx]  = s2[b*NN + idx];
    mpls[idx] = mpl[b*NN + idx];
  }
  const int prow = t >> 2;
  const int kq = (t & 3) * 8;
  const int i = it*64 + prow;
  const float s1i = s1[b*NN + i];
  const unsigned long long* mrow = mask + (size_t)(b*NN + i)*32;
  const unsigned short* vsrc0 = hbT + (size_t)(b*FO + ot*128 + prow)*NN;
  const unsigned short* vsrc1 = hbT + (size_t)(b*FO + ot*128 + prow + 64)*NN;
  const int lane = t & 63, wv = t >> 6;
  const int wr = (wv & 1)*32;
  const int wc = (wv >> 1)*64;
  const int ln = lane & 15, q8 = (lane >> 4)*8;
  floatx4 acc[2][4];
  #pragma unroll
  for (int mb = 0; mb < 2; ++mb)
    #pragma unroll
    for (int nb = 0; nb < 4; ++nb)
      acc[mb][nb] = (floatx4){0.f, 0.f, 0.f, 0.f};
  __syncthreads();
  for (int kt = 0; kt < NN/32; ++kt) {
    const int j0 = kt*32;
    const unsigned int bits =
        (unsigned int)(mrow[j0 >> 6] >> (j0 & 63)) >> kq;
    __align__(16) unsigned short pv[8];
    #pragma unroll
    for (int kk = 0; kk < 8; ++kk) {
      const int k = j0 + kq + kk;
      float e = s1i + s2s[k];
      e = fmaxf(e, ALPHA*e);
      const float vvv = ((bits >> kk) & 1u) ? e : NEG_BIG;
      pv[kk] = __builtin_bit_cast(unsigned short,
                 __float2bfloat16(__expf(vvv - mpls[k])));
    }
    *(uint4*)&Pt[prow*40 + kq] = *(const uint4*)pv;
    *(uint4*)&Vt[prow*40 + kq]      = *(const uint4*)(vsrc0 + j0 + kq);
    *(uint4*)&Vt[(prow+64)*40 + kq] = *(const uint4*)(vsrc1 + j0 + kq);
    __syncthreads();
    bf16x8 af[2], bfr[4];
    #pragma unroll
    for (int mb = 0; mb < 2; ++mb)
      af[mb] = *(const bf16x8*)&Pt[(wr + mb*16 + ln)*40 + q8];
    #pragma unroll
    for (int nb = 0; nb < 4; ++nb)
      bfr[nb] = *(const bf16x8*)&Vt[(wc + nb*16 + ln)*40 + q8];
    #pragma unroll
    for (int mb = 0; mb < 2; ++mb)
      #pragma unroll
      for (int nb = 0; nb < 4; ++nb)
        acc[mb][nb] = __builtin_amdgcn_mfma_f32_16x16x32_bf16(
            af[mb], bfr[nb], acc[mb][nb], 0, 0, 0);
    __syncthreads();
  }
  const int orow_base = it*64 + wr;
  const int ocol_base = ot*128 + wc;
  #pragma unroll
  for (int mb = 0; mb < 2; ++mb) {
    #pragma unroll
    for (int nb = 0; nb < 4; ++nb) {
      #pragma unroll
      for (int r = 0; r < 4; ++r) {
        float vvv = acc[mb][nb][r];
        vvv = vvv > 0.f ? vvv : (__expf(vvv) - 1.f);
        const int m_loc = orow_base + mb*16 + (lane >> 4)*4 + r;
        const int n_loc = ocol_base + nb*16 + ln;
        out[(size_t)(b*NN + m_loc)*FO + n_loc] = vvv;
      }
    }
  }
}

extern "C" void kernel_launch(void* const* d_in, const int* in_sizes, int n_in,
                              void* d_out, int out_size, void* d_ws, size_t ws_size,
                              hipStream_t stream) {
  const float* x  = (const float*)d_in[0];
  const int* adj  = (const int*)d_in[1];
  const float* W  = (const float*)d_in[2];
  const float* a  = (const float*)d_in[3];
  float* out = (float*)d_out;

  char* ws = (char*)d_ws;
  size_t off = 0;
  auto alloc = [&](size_t bytes) -> void* {
    void* p = ws + off; off += (bytes + 255) & ~(size_t)255; return p;
  };
  unsigned short* hbT      = (unsigned short*)alloc((size_t)BATCH*FO*NN*2);      // 8 MB
  float* s1                = (float*)alloc((size_t)BATCH*NN*4);
  float* s2                = (float*)alloc((size_t)BATCH*NN*4);
  float* pm                = (float*)alloc((size_t)8*BATCH*NN*4);
  float* pl                = (float*)alloc((size_t)8*BATCH*NN*4);
  float* mpl               = (float*)alloc((size_t)BATCH*NN*4);
  unsigned long long* mask = (unsigned long long*)alloc((size_t)BATCH*NN*(NN/64)*8); // 4 MB

  mask_kernel<<<dim3(BATCH*NN*(NN/64)/256), dim3(256), 0, stream>>>(adj, mask);
  gemm_h_kernel<<<dim3(BATCH*NN/16), dim3(256), 0, stream>>>(x, W, a, hbT, s1, s2);
  stats2_kernel<<<dim3(8, 8, 8), dim3(256), 0, stream>>>(mask, s1, s2, pm, pl);
  combine_kernel<<<dim3(BATCH*NN/256), dim3(256), 0, stream>>>(pm, pl, mpl);
  agg_kernel<<<dim3(2, NN/64, BATCH), dim3(256), 0, stream>>>(mask, s1, s2, mpl, hbT, out);
}

// Round 4
// 293.863 us; speedup vs baseline: 1.4403x; 1.1697x over previous
//
#include <hip/hip_runtime.h>
#include <hip/hip_bf16.h>

#define BATCH 8
#define NN 2048
#define FI 256
#define FO 256
#define ALPHA 0.2f
#define NEG_BIG -9000000000000000.0f

typedef short bf16x8 __attribute__((ext_vector_type(8)));
typedef float floatx4 __attribute__((ext_vector_type(4)));

static __device__ __forceinline__ unsigned short f2bf(float f) {
  return __builtin_bit_cast(unsigned short, __float2bfloat16(f));
}
static __device__ __forceinline__ float bf2f(unsigned short u) {
  unsigned int x = ((unsigned int)u) << 16;
  return __builtin_bit_cast(float, x);
}

// ---------------- K0: prep — WT (bf16, [o][f]) + wa1/wa2 = W@a halves -------
__global__ __launch_bounds__(256) void prep_kernel(
    const float* __restrict__ W, const float* __restrict__ a,
    unsigned short* __restrict__ WT, float* __restrict__ wa1, float* __restrict__ wa2) {
  const int t = threadIdx.x;
  const int blk = blockIdx.x;
  if (blk < 64) {
    __shared__ float xt[32][33];
    const int tr = blk >> 3, tc = blk & 7;        // f-tile, o-tile
    const int r = t >> 3, o4 = t & 7;
    const float4 v = *(const float4*)(W + (size_t)(tr*32 + r)*FO + tc*32 + o4*4);
    xt[o4*4+0][r] = v.x; xt[o4*4+1][r] = v.y; xt[o4*4+2][r] = v.z; xt[o4*4+3][r] = v.w;
    __syncthreads();
    const int ol = t >> 3, f4 = t & 7;
    unsigned short u4[4];
    #pragma unroll
    for (int u = 0; u < 4; ++u) u4[u] = f2bf(xt[ol][f4*4 + u]);
    *(uint2*)(WT + (size_t)(tc*32 + ol)*FI + tr*32 + f4*4) = *(const uint2*)u4;
  } else {
    const int bk = blk - 64;
    const int f = bk*32 + (t >> 3), oc = t & 7;
    const float4* wrow = (const float4*)(W + (size_t)f*FO) + oc*8;
    const float4* a1v  = (const float4*)a + oc*8;
    const float4* a2v  = (const float4*)(a + FO) + oc*8;
    float p1 = 0.f, p2 = 0.f;
    #pragma unroll
    for (int i = 0; i < 8; ++i) {
      const float4 w = wrow[i], b1 = a1v[i], b2 = a2v[i];
      p1 += w.x*b1.x + w.y*b1.y + w.z*b1.z + w.w*b1.w;
      p2 += w.x*b2.x + w.y*b2.y + w.z*b2.z + w.w*b2.w;
    }
    p1 += __shfl_xor(p1, 1); p2 += __shfl_xor(p2, 1);
    p1 += __shfl_xor(p1, 2); p2 += __shfl_xor(p2, 2);
    p1 += __shfl_xor(p1, 4); p2 += __shfl_xor(p2, 4);
    if (oc == 0) { wa1[f] = p1; wa2[f] = p2; }
  }
}

// ---------------- K1: hT = (x@W)^T via bf16 MFMA, fused s1/s2 ---------------
__global__ __launch_bounds__(256) void hgemm_kernel(
    const float* __restrict__ x, const unsigned short* __restrict__ WT,
    const float* __restrict__ wa1, const float* __restrict__ wa2,
    unsigned short* __restrict__ hbT, float* __restrict__ s1, float* __restrict__ s2) {
  const int t = threadIdx.x;
  const int nt = blockIdx.x, ot = blockIdx.y, b = blockIdx.z;
  const int n0 = nt*64, o0 = ot*128;
  __shared__ __align__(16) unsigned short xs[64][72];
  __shared__ __align__(16) unsigned short ws[128][72];
  __shared__ float was[256];
  was[t] = (ot == 0) ? wa1[t] : wa2[t];
  const int lane = t & 63, wv = t >> 6;
  const int wr = (wv & 1)*32, wc = (wv >> 1)*64;
  const int ln = lane & 15, q8 = (lane >> 4)*8;
  const int srow = t >> 2, fq = (t & 3)*16;
  floatx4 acc[2][4];
  #pragma unroll
  for (int mb = 0; mb < 2; ++mb)
    #pragma unroll
    for (int nb = 0; nb < 4; ++nb) acc[mb][nb] = (floatx4){0.f,0.f,0.f,0.f};
  float sp = 0.f;
  for (int kt = 0; kt < 4; ++kt) {
    const int f0 = kt*64;
    #pragma unroll
    for (int p = 0; p < 4; ++p) {          // stage x 64n x 64f fp32 -> bf16
      const int idx = p*256 + t;
      const int row = idx >> 4, c4 = idx & 15;
      const float4 v = *(const float4*)(x + (size_t)(b*NN + n0 + row)*FI + f0 + c4*4);
      unsigned short u4[4] = {f2bf(v.x), f2bf(v.y), f2bf(v.z), f2bf(v.w)};
      *(uint2*)&xs[row][c4*4] = *(const uint2*)u4;
    }
    #pragma unroll
    for (int p = 0; p < 4; ++p) {          // stage WT 128o x 64f (8 shorts = uint4!)
      const int idx = p*256 + t;
      const int o = idx >> 3, f8 = idx & 7;
      *(uint4*)&ws[o][f8*8] = *(const uint4*)(WT + (size_t)(o0 + o)*FI + f0 + f8*8);
    }
    __syncthreads();
    {                                      // s partial: 16 f per thread
      const bf16x8 h0 = *(const bf16x8*)&xs[srow][fq];
      const bf16x8 h1 = *(const bf16x8*)&xs[srow][fq + 8];
      #pragma unroll
      for (int u = 0; u < 8; ++u) {
        sp = fmaf(bf2f((unsigned short)h0[u]), was[f0 + fq + u], sp);
        sp = fmaf(bf2f((unsigned short)h1[u]), was[f0 + fq + 8 + u], sp);
      }
    }
    #pragma unroll
    for (int ks = 0; ks < 2; ++ks) {
      bf16x8 af[2], bfr[4];
      #pragma unroll
      for (int mb = 0; mb < 2; ++mb)
        af[mb] = *(const bf16x8*)&xs[wr + mb*16 + ln][ks*32 + q8];
      #pragma unroll
      for (int nb = 0; nb < 4; ++nb)
        bfr[nb] = *(const bf16x8*)&ws[wc + nb*16 + ln][ks*32 + q8];
      #pragma unroll
      for (int mb = 0; mb < 2; ++mb)
        #pragma unroll
        for (int nb = 0; nb < 4; ++nb)
          acc[mb][nb] = __builtin_amdgcn_mfma_f32_16x16x32_bf16(
              af[mb], bfr[nb], acc[mb][nb], 0, 0, 0);
    }
    __syncthreads();
  }
  sp += __shfl_xor(sp, 1);
  sp += __shfl_xor(sp, 2);
  if ((t & 3) == 0) {
    float* sdst = (ot == 0) ? s1 : s2;
    sdst[b*NN + n0 + srow] = sp;
  }
  const int quad = lane >> 4;
  #pragma unroll
  for (int mb = 0; mb < 2; ++mb)
    #pragma unroll
    for (int nb = 0; nb < 4; ++nb) {
      unsigned short u4[4];
      #pragma unroll
      for (int r = 0; r < 4; ++r) u4[r] = f2bf(acc[mb][nb][r]);
      const int o_loc = wc + nb*16 + ln;
      const int n_loc = wr + mb*16 + quad*4;
      *(uint2*)(hbT + (size_t)(b*FO + o0 + o_loc)*NN + n0 + n_loc) = *(const uint2*)u4;
    }
}

// ---------------- K2: adj -> mask32 + column softmax partials (one pass) -----
__global__ __launch_bounds__(256) void adjstats_kernel(
    const int* __restrict__ adj, const float* __restrict__ s1, const float* __restrict__ s2,
    unsigned int* __restrict__ mask32, float* __restrict__ pm, float* __restrict__ pl) {
  const int t = threadIdx.x;
  const int jt = blockIdx.x, ic = blockIdx.y, b = blockIdx.z;
  const int i0 = ic*256;
  __shared__ unsigned short bitsm[16][260];   // [j16][i], pad 260 vs 256
  __shared__ float s1s[256];
  s1s[t] = s1[b*NN + i0 + t];
  const int rr = t >> 4, j16 = t & 15;
  #pragma unroll 4
  for (int p = 0; p < 16; ++p) {
    const int row = p*16 + rr;
    const int4* src = (const int4*)(adj + (size_t)(b*NN + i0 + row)*NN + jt*256 + j16*16);
    const int4 q0 = src[0], q1 = src[1], q2 = src[2], q3 = src[3];
    unsigned int m = 0;
    m |= (unsigned int)(q0.x != 0) << 0;  m |= (unsigned int)(q0.y != 0) << 1;
    m |= (unsigned int)(q0.z != 0) << 2;  m |= (unsigned int)(q0.w != 0) << 3;
    m |= (unsigned int)(q1.x != 0) << 4;  m |= (unsigned int)(q1.y != 0) << 5;
    m |= (unsigned int)(q1.z != 0) << 6;  m |= (unsigned int)(q1.w != 0) << 7;
    m |= (unsigned int)(q2.x != 0) << 8;  m |= (unsigned int)(q2.y != 0) << 9;
    m |= (unsigned int)(q2.z != 0) << 10; m |= (unsigned int)(q2.w != 0) << 11;
    m |= (unsigned int)(q3.x != 0) << 12; m |= (unsigned int)(q3.y != 0) << 13;
    m |= (unsigned int)(q3.z != 0) << 14; m |= (unsigned int)(q3.w != 0) << 15;
    bitsm[j16][row] = (unsigned short)m;
  }
  __syncthreads();
  #pragma unroll
  for (int p = 0; p < 8; ++p) {               // coalesced mask32 write
    const int idx = p*256 + t;
    const int il = idx >> 3, wl = idx & 7;
    const unsigned int d = (unsigned int)bitsm[2*wl][il]
                         | ((unsigned int)bitsm[2*wl + 1][il] << 16);
    mask32[(size_t)(b*NN + i0 + il)*64 + jt*8 + wl] = d;
  }
  const int j = jt*256 + t;
  const float s2j = s2[b*NN + j];
  const int c16 = t >> 4, sh = t & 15;
  float M0 = NEG_BIG, M1 = NEG_BIG, M2 = NEG_BIG, M3 = NEG_BIG;
  for (int i = 0; i < 256; i += 4) {
    const uint2 w = *(const uint2*)&bitsm[c16][i];
    M0 = fmaxf(M0, ((w.x >> sh) & 1u)        ? s1s[i+0] : NEG_BIG);
    M1 = fmaxf(M1, ((w.x >> (16+sh)) & 1u)   ? s1s[i+1] : NEG_BIG);
    M2 = fmaxf(M2, ((w.y >> sh) & 1u)        ? s1s[i+2] : NEG_BIG);
    M3 = fmaxf(M3, ((w.y >> (16+sh)) & 1u)   ? s1s[i+3] : NEG_BIG);
  }
  const float M = fmaxf(fmaxf(M0, M1), fmaxf(M2, M3));
  float m;
  if (M == NEG_BIG) m = NEG_BIG;
  else { const float e = M + s2j; m = fmaxf(e, ALPHA*e); }
  float l0 = 0.f, l1 = 0.f, l2 = 0.f, l3 = 0.f;
  for (int i = 0; i < 256; i += 4) {
    const uint2 w = *(const uint2*)&bitsm[c16][i];
    float e0 = s1s[i+0] + s2j; e0 = fmaxf(e0, ALPHA*e0);
    float e1 = s1s[i+1] + s2j; e1 = fmaxf(e1, ALPHA*e1);
    float e2 = s1s[i+2] + s2j; e2 = fmaxf(e2, ALPHA*e2);
    float e3 = s1s[i+3] + s2j; e3 = fmaxf(e3, ALPHA*e3);
    l0 += __expf((((w.x >> sh) & 1u)      ? e0 : NEG_BIG) - m);
    l1 += __expf((((w.x >> (16+sh)) & 1u) ? e1 : NEG_BIG) - m);
    l2 += __expf((((w.y >> sh) & 1u)      ? e2 : NEG_BIG) - m);
    l3 += __expf((((w.y >> (16+sh)) & 1u) ? e3 : NEG_BIG) - m);
  }
  pm[(ic*BATCH + b)*NN + j] = m;
  pl[(ic*BATCH + b)*NN + j] = (l0 + l1) + (l2 + l3);
}

// ---------------- K3: out = elu(P @ h), P on the fly; combine folded in -----
__global__ __launch_bounds__(256) void agg_kernel(
    const unsigned int* __restrict__ mask32, const float* __restrict__ s1,
    const float* __restrict__ s2, const float* __restrict__ pm, const float* __restrict__ pl,
    const unsigned short* __restrict__ hbT, float* __restrict__ out) {
  const int t = threadIdx.x;
  const int ot = blockIdx.x, it = blockIdx.y, b = blockIdx.z;
  __shared__ __align__(16) unsigned short Pt[64*40];
  __shared__ __align__(16) unsigned short Vt[128*40];
  __shared__ float s2s[NN];
  __shared__ float mpls[NN];
  #pragma unroll
  for (int q = 0; q < 8; ++q) {               // combine: mpl = m + log l
    const int j = q*256 + t;
    float m = NEG_BIG;
    #pragma unroll
    for (int c = 0; c < 8; ++c) m = fmaxf(m, pm[(c*BATCH + b)*NN + j]);
    float l = 0.f;
    #pragma unroll
    for (int c = 0; c < 8; ++c)
      l += pl[(c*BATCH + b)*NN + j] * __expf(pm[(c*BATCH + b)*NN + j] - m);
    mpls[j] = m + __logf(l);
    s2s[j] = s2[b*NN + j];
  }
  const int prow = t >> 2;
  const int kq = (t & 3) * 8;
  const int i = it*64 + prow;
  const float s1i = s1[b*NN + i];
  const unsigned int* m32row = mask32 + (size_t)(b*NN + i)*64;
  const unsigned short* vsrc0 = hbT + (size_t)(b*FO + ot*128 + prow)*NN;
  const unsigned short* vsrc1 = hbT + (size_t)(b*FO + ot*128 + prow + 64)*NN;
  const int lane = t & 63, wv = t >> 6;
  const int wr = (wv & 1)*32;
  const int wc = (wv >> 1)*64;
  const int ln = lane & 15, q8 = (lane >> 4)*8;
  floatx4 acc[2][4];
  #pragma unroll
  for (int mb = 0; mb < 2; ++mb)
    #pragma unroll
    for (int nb = 0; nb < 4; ++nb) acc[mb][nb] = (floatx4){0.f,0.f,0.f,0.f};
  __syncthreads();
  for (int kt = 0; kt < NN/32; ++kt) {
    const int j0 = kt*32;
    const unsigned int bits = m32row[kt] >> kq;
    __align__(16) unsigned short pv[8];
    #pragma unroll
    for (int kk = 0; kk < 8; ++kk) {
      const int k = j0 + kq + kk;
      float e = s1i + s2s[k];
      e = fmaxf(e, ALPHA*e);
      const float vvv = ((bits >> kk) & 1u) ? e : NEG_BIG;
      pv[kk] = f2bf(__expf(vvv - mpls[k]));
    }
    *(uint4*)&Pt[prow*40 + kq] = *(const uint4*)pv;
    *(uint4*)&Vt[prow*40 + kq]      = *(const uint4*)(vsrc0 + j0 + kq);
    *(uint4*)&Vt[(prow+64)*40 + kq] = *(const uint4*)(vsrc1 + j0 + kq);
    __syncthreads();
    bf16x8 af[2], bfr[4];
    #pragma unroll
    for (int mb = 0; mb < 2; ++mb)
      af[mb] = *(const bf16x8*)&Pt[(wr + mb*16 + ln)*40 + q8];
    #pragma unroll
    for (int nb = 0; nb < 4; ++nb)
      bfr[nb] = *(const bf16x8*)&Vt[(wc + nb*16 + ln)*40 + q8];
    #pragma unroll
    for (int mb = 0; mb < 2; ++mb)
      #pragma unroll
      for (int nb = 0; nb < 4; ++nb)
        acc[mb][nb] = __builtin_amdgcn_mfma_f32_16x16x32_bf16(
            af[mb], bfr[nb], acc[mb][nb], 0, 0, 0);
    __syncthreads();
  }
  const int orow_base = it*64 + wr;
  const int ocol_base = ot*128 + wc;
  #pragma unroll
  for (int mb = 0; mb < 2; ++mb)
    #pragma unroll
    for (int nb = 0; nb < 4; ++nb)
      #pragma unroll
      for (int r = 0; r < 4; ++r) {
        float vvv = acc[mb][nb][r];
        vvv = vvv > 0.f ? vvv : (__expf(vvv) - 1.f);
        const int m_loc = orow_base + mb*16 + (lane >> 4)*4 + r;
        const int n_loc = ocol_base + nb*16 + ln;
        out[(size_t)(b*NN + m_loc)*FO + n_loc] = vvv;
      }
}

extern "C" void kernel_launch(void* const* d_in, const int* in_sizes, int n_in,
                              void* d_out, int out_size, void* d_ws, size_t ws_size,
                              hipStream_t stream) {
  const float* x  = (const float*)d_in[0];
  const int* adj  = (const int*)d_in[1];
  const float* W  = (const float*)d_in[2];
  const float* a  = (const float*)d_in[3];
  float* out = (float*)d_out;

  char* ws = (char*)d_ws;
  size_t off = 0;
  auto alloc = [&](size_t bytes) -> void* {
    void* p = ws + off; off += (bytes + 255) & ~(size_t)255; return p;
  };
  unsigned short* WT   = (unsigned short*)alloc((size_t)FI*FO*2);            // 128 KB
  float* wa1           = (float*)alloc(FO*4);
  float* wa2           = (float*)alloc(FO*4);
  unsigned short* hbT  = (unsigned short*)alloc((size_t)BATCH*FO*NN*2);      // 8 MB
  float* s1            = (float*)alloc((size_t)BATCH*NN*4);
  float* s2            = (float*)alloc((size_t)BATCH*NN*4);
  float* pm            = (float*)alloc((size_t)8*BATCH*NN*4);
  float* pl            = (float*)alloc((size_t)8*BATCH*NN*4);
  unsigned int* mask32 = (unsigned int*)alloc((size_t)BATCH*NN*(NN/32)*4);   // 4 MB

  prep_kernel<<<dim3(72), dim3(256), 0, stream>>>(W, a, WT, wa1, wa2);
  hgemm_kernel<<<dim3(32, 2, BATCH), dim3(256), 0, stream>>>(x, WT, wa1, wa2, hbT, s1, s2);
  adjstats_kernel<<<dim3(8, 8, BATCH), dim3(256), 0, stream>>>(adj, s1, s2, mask32, pm, pl);
  agg_kernel<<<dim3(2, NN/64, BATCH), dim3(256), 0, stream>>>(mask32, s1, s2, pm, pl, hbT, out);
}